// Round 11
// baseline (228.900 us; speedup 1.0000x reference)
//
#include <hip/hip_runtime.h>

#define TT 512
#define BB 64
#define DD 768
#define NEG (-1e30f)

__device__ __forceinline__ float fmax3(float a, float b, float c) {
    return fmaxf(fmaxf(a, b), c);
}
__device__ __forceinline__ int imin3(int a, int b, int c) {
    return min(min(a, b), c);
}
__device__ __forceinline__ float rl(float x, int i) {
    return __int_as_float(__builtin_amdgcn_readlane(__float_as_int(x), i));
}
__device__ __forceinline__ float dot4(float4 a, float4 b) {
    return a.x * b.x + a.y * b.y + a.z * b.z + a.w * b.w;
}
__device__ __forceinline__ void gl_lds16(const float* g, float* l) {
    __builtin_amdgcn_global_load_lds(
        (const __attribute__((address_space(1))) void*)g,
        (__attribute__((address_space(3))) void*)l, 16, 0, 0);
}

// ---------------------------------------------------------------------------
// Kernel 1: fused GEMM + lse chunk matrices.
// 512 blocks; block g = 8b+k owns rows/timesteps [64k, 64k+64) of sequence b.
// GEMM: r10 scheme (global_load_lds dbuf, xor swizzle, 2 blocks/CU).
// Then, with logits in LDS, the block's 4 waves compute the two 32-step lse
// transfer matrices for chunks 2k, 2k+1 (chunk c = steps t in
// [max(1,c*32), c*32+31] -- boundary-shifted chunking, pure reassociation).
// ---------------------------------------------------------------------------
__global__ __launch_bounds__(256) void gemm_lse_kernel(
    const float* __restrict__ x,
    const float* __restrict__ W1, const float* __restrict__ b1,
    const float* __restrict__ W2, const float* __restrict__ b2,
    const int* __restrict__ seqlen,
    const float* __restrict__ trans1, const float* __restrict__ trans2,
    float* __restrict__ o1, float* __restrict__ o2,
    float* __restrict__ M1, float* __restrict__ M2)
{
    __shared__ float wT[11][DD];
    __shared__ float x_tile[2][64 * 64];
    __shared__ float s_l2[64][9];
    __shared__ float s_l1[64][2];

    const int tid = threadIdx.x;
    const int wave = tid >> 6, lane = tid & 63;

    for (int i = tid; i < 11 * DD; i += 256) {
        int m = i / DD, d = i - m * DD;
        wT[m][d] = (m < 2) ? W1[d * 2 + m] : W2[d * 9 + (m - 2)];
    }

    const int row0 = blockIdx.x * 64;
#define STAGE_TILE(KT, BF) { \
        _Pragma("unroll") \
        for (int i = 0; i < 4; ++i) { \
            const int e = i * 256 + tid; \
            const int r = e >> 4, q = e & 15; \
            const int qg = q ^ (r & 15); \
            const float* gp = x + ((size_t)(row0 + r) * DD + (KT) * 64 + qg * 4); \
            gl_lds16(gp, &x_tile[BF][e * 4]); \
        } }

    STAGE_TILE(0, 0);
    __syncthreads();

    const int c = lane & 7, g = lane >> 3;
    const int rw = wave * 16;

    float acc[2][11];
#pragma unroll
    for (int j = 0; j < 2; ++j)
#pragma unroll
        for (int m = 0; m < 11; ++m) acc[j][m] = 0.f;

    for (int kt = 0; kt < 12; ++kt) {
        const int cur = kt & 1;
        if (kt + 1 < 12) STAGE_TILE(kt + 1, cur ^ 1);

        float4 xa[2], xb[2];
#pragma unroll
        for (int j = 0; j < 2; ++j) {
            const int r = rw + g + 8 * j;
            const int s = r & 15;
            const int pA = (2 * c) ^ s, pB = (2 * c + 1) ^ s;
            xa[j] = *(const float4*)&x_tile[cur][r * 64 + pA * 4];
            xb[j] = *(const float4*)&x_tile[cur][r * 64 + pB * 4];
        }
#pragma unroll
        for (int m = 0; m < 11; ++m) {
            const float* wp = &wT[m][kt * 64 + c * 8];
            float4 wa = *(const float4*)(wp);
            float4 wb = *(const float4*)(wp + 4);
#pragma unroll
            for (int j = 0; j < 2; ++j)
                acc[j][m] += dot4(xa[j], wa) + dot4(xb[j], wb);
        }
        __syncthreads();
    }

#pragma unroll
    for (int j = 0; j < 2; ++j)
#pragma unroll
        for (int m = 0; m < 11; ++m) {
            acc[j][m] += __shfl_xor(acc[j][m], 1);
            acc[j][m] += __shfl_xor(acc[j][m], 2);
            acc[j][m] += __shfl_xor(acc[j][m], 4);
        }

    if (c == 0) {
        float bb1[2] = { b1[0], b1[1] };
        float bb2[9];
#pragma unroll
        for (int m = 0; m < 9; ++m) bb2[m] = b2[m];
#pragma unroll
        for (int j = 0; j < 2; ++j) {
            const int tl = rw + g + 8 * j;          // tile-local timestep
            const int row = row0 + tl;              // global row
            float v0 = acc[j][0] + bb1[0], v1 = acc[j][1] + bb1[1];
            o1[row * 2 + 0] = v0; o1[row * 2 + 1] = v1;
            s_l1[tl][0] = v0;     s_l1[tl][1] = v1;
#pragma unroll
            for (int m = 0; m < 9; ++m) {
                float vv = acc[j][m + 2] + bb2[m];
                o2[row * 9 + m] = vv;
                s_l2[tl][m] = vv;
            }
        }
    }
    __syncthreads();

    // ---------------- lse chunk transfer matrices ----------------
    const int b = blockIdx.x >> 3, k = blockIdx.x & 7;
    const int sl = seqlen[b];
    const int team = wave >> 1;          // 0 or 1
    const int wpar = wave & 1;           // parity within team
    const int cch = 2 * k + team;
    const int t0c = cch * 32;
    int tstart = (t0c < 1) ? 1 : t0c;
    int tend = t0c + 32; if (tend > sl) tend = sl;

    int L, i_row, jj, base2; bool active;
    if (wpar == 0) {
        if (lane < 63) { active = true;  L = 9; i_row = lane / 9; jj = lane - i_row * 9; base2 = i_row * 9; }
        else           { active = false; L = 9; i_row = 0; jj = 0; base2 = 54; }
    } else {
        if (lane < 18)      { active = true;  L = 9; i_row = 7 + lane / 9; jj = lane % 9; base2 = (lane / 9) * 9; }
        else if (lane < 22) { active = true;  L = 2; i_row = (lane - 18) >> 1; jj = (lane - 18) & 1; base2 = 18 + ((lane - 18) & ~1); }
        else                { active = false; L = 2; i_row = 0; jj = 0; base2 = 18; }
    }

    float tcol[9], row[9];
#pragma unroll
    for (int q = 0; q < 9; ++q) {
        tcol[q] = (q < L) ? ((L == 9) ? trans2[q * 9 + jj] : trans1[q * 2 + jj]) : NEG;
        row[q]  = (q < L && q == i_row) ? 0.f : NEG;
    }

    for (int t = tstart; t < tend; ++t) {
        const int tl = t - k * 64;
        float l = (L == 9) ? s_l2[tl][jj] : s_l1[tl][jj];
        float v[9];
#pragma unroll
        for (int q = 0; q < 9; ++q) v[q] = row[q] + tcol[q];
        float m = fmax3(fmax3(v[0], v[1], v[2]), fmax3(v[3], v[4], v[5]), fmax3(v[6], v[7], v[8]));
        float s = 0.f;
#pragma unroll
        for (int q = 0; q < 9; ++q) s += __expf(v[q] - m);
        float nv = m + __logf(s) + l;
#pragma unroll
        for (int q = 0; q < 9; ++q) {
            float sv = __shfl(nv, base2 + (q < L ? q : 0));
            row[q] = (q < L) ? sv : NEG;
        }
    }
    if (active) {
        if (L == 9) M2[((size_t)(b * 16 + cch)) * 81 + i_row * 9 + jj] = row[jj];
        else        M1[((size_t)(b * 16 + cch)) * 4  + i_row * 2 + jj] = row[jj];
    }
#undef STAGE_TILE
}

// ---------------------------------------------------------------------------
// Kernel 2: per-sequence exact Viterbi + backtrace + tags + counts + scores
// + ll fold (M matrices staged in LDS; stream order guarantees M ready).
// Grid 64 x 256.
// ---------------------------------------------------------------------------
__global__ __launch_bounds__(256) void viterbi_kernel(
    const float* __restrict__ o1, const float* __restrict__ o2,
    const int* __restrict__ label, const int* __restrict__ seqlen,
    const float* __restrict__ trans1, const float* __restrict__ trans2,
    const float* __restrict__ M1, const float* __restrict__ M2,
    float* __restrict__ dout,
    float* __restrict__ counts, float* __restrict__ ll1, float* __restrict__ ll2)
{
    __shared__ float s_l2[TT][9];
    __shared__ float s_l1[TT][2];
    __shared__ float s_alpha2[TT][9];
    __shared__ float s_alpha1[TT][2];
    __shared__ int   s_lab[TT];
    __shared__ float s_tr2[81];
    __shared__ float s_tr1[4];
    __shared__ float sM2[16 * 81];
    __shared__ float sM1[16 * 4];
    __shared__ unsigned char s_bp2[9][TT];
    __shared__ unsigned char s_bp1[2][TT];
    __shared__ unsigned char s_path2[16][9][36];
    __shared__ unsigned char s_path1[16][2][36];
    __shared__ unsigned char s_sel2[16], s_sel1[16];
    __shared__ float s_part[2][4];
    __shared__ int s_last2, s_last1;
    __shared__ int s_cnt[4][3];

    const int tid  = threadIdx.x;
    const int wave = tid >> 6, lane = tid & 63;
    const int b  = blockIdx.x;
    const int sl = seqlen[b];

    // phase 0: staging
    {
        const float4* src = (const float4*)(o2 + (size_t)b * TT * 9);
        float4* dst = (float4*)&s_l2[0][0];
        for (int i = tid; i < TT * 9 / 4; i += 256) dst[i] = src[i];
    }
    {
        const float4* src = (const float4*)(o1 + (size_t)b * TT * 2);
        float4* dst = (float4*)&s_l1[0][0];
        for (int i = tid; i < TT * 2 / 4; i += 256) dst[i] = src[i];
    }
    {
        const int4* src = (const int4*)(label + (size_t)b * TT);
        int4* dst = (int4*)s_lab;
        for (int i = tid; i < TT / 4; i += 256) dst[i] = src[i];
    }
    for (int i = tid; i < 16 * 81; i += 256) sM2[i] = M2[(size_t)b * 16 * 81 + i];
    for (int i = tid; i < 16 * 4;  i += 256) sM1[i] = M1[(size_t)b * 16 * 4 + i];
    if (tid < 81) s_tr2[tid] = trans2[tid];
    if (tid >= 96 && tid < 100) s_tr1[tid - 96] = trans1[tid - 96];
    for (int i = tid; i < 9 * TT; i += 256) ((unsigned char*)s_bp2)[i] = (unsigned char)(i >> 9);
    for (int i = tid; i < 2 * TT; i += 256) ((unsigned char*)s_bp1)[i] = (unsigned char)(i >> 9);
    __syncthreads();

    // phase 1: lean forward scans (alpha-store only) + score sums
    if (wave == 0) {
        if (lane < 9) {
            const int j = lane;
            float tc0 = s_tr2[0 * 9 + j], tc1 = s_tr2[1 * 9 + j], tc2 = s_tr2[2 * 9 + j];
            float tc3 = s_tr2[3 * 9 + j], tc4 = s_tr2[4 * 9 + j], tc5 = s_tr2[5 * 9 + j];
            float tc6 = s_tr2[6 * 9 + j], tc7 = s_tr2[7 * 9 + j], tc8 = s_tr2[8 * 9 + j];
            float av = s_l2[0][j];
            s_alpha2[0][j] = av;
            float a0 = rl(av, 0), a1 = rl(av, 1), a2 = rl(av, 2);
            float a3 = rl(av, 3), a4 = rl(av, 4), a5 = rl(av, 5);
            float a6 = rl(av, 6), a7 = rl(av, 7), a8 = rl(av, 8);

#define VSTEP2(T, LG) { \
            float v0=a0+tc0, v1=a1+tc1, v2=a2+tc2, v3=a3+tc3, v4=a4+tc4; \
            float v5=a5+tc5, v6=a6+tc6, v7=a7+tc7, v8=a8+tc8; \
            float mm = fmax3(fmax3(v0,v1,v2), fmax3(v3,v4,v5), fmax3(v6,v7,v8)); \
            float nj = mm + (LG); \
            s_alpha2[T][j] = nj; \
            a0=rl(nj,0); a1=rl(nj,1); a2=rl(nj,2); a3=rl(nj,3); a4=rl(nj,4); \
            a5=rl(nj,5); a6=rl(nj,6); a7=rl(nj,7); a8=rl(nj,8); }

            for (int t = 1; t < 8 && t < sl; ++t) {
                float lg = s_l2[t][j];
                VSTEP2(t, lg);
            }
            int t0 = 8;
            for (; t0 + 8 <= sl; t0 += 8) {
                float l0 = s_l2[t0 + 0][j], l1 = s_l2[t0 + 1][j];
                float l2 = s_l2[t0 + 2][j], l3 = s_l2[t0 + 3][j];
                float l4 = s_l2[t0 + 4][j], l5 = s_l2[t0 + 5][j];
                float l6 = s_l2[t0 + 6][j], l7 = s_l2[t0 + 7][j];
                VSTEP2(t0 + 0, l0); VSTEP2(t0 + 1, l1);
                VSTEP2(t0 + 2, l2); VSTEP2(t0 + 3, l3);
                VSTEP2(t0 + 4, l4); VSTEP2(t0 + 5, l5);
                VSTEP2(t0 + 6, l6); VSTEP2(t0 + 7, l7);
            }
            for (int t = t0; t < sl; ++t) {
                float lg = s_l2[t][j];
                VSTEP2(t, lg);
            }
#undef VSTEP2
            if (lane == 0) {
                float mm = fmax3(fmax3(a0, a1, a2), fmax3(a3, a4, a5), fmax3(a6, a7, a8));
                int c0 = (a0 == mm) ? 0 : 15, c1 = (a1 == mm) ? 1 : 15, c2 = (a2 == mm) ? 2 : 15;
                int c3 = (a3 == mm) ? 3 : 15, c4 = (a4 == mm) ? 4 : 15, c5 = (a5 == mm) ? 5 : 15;
                int c6 = (a6 == mm) ? 6 : 15, c7 = (a7 == mm) ? 7 : 15, c8 = (a8 == mm) ? 8 : 15;
                s_last2 = imin3(imin3(c0, c1, c2), imin3(c3, c4, c5), imin3(c6, c7, c8));
            }
        }
    } else if (wave == 1) {
        if (lane < 2) {
            const int j = lane;
            float tc0 = s_tr1[0 * 2 + j], tc1 = s_tr1[1 * 2 + j];
            float av = s_l1[0][j];
            s_alpha1[0][j] = av;
            float a0 = rl(av, 0), a1 = rl(av, 1);

#define VSTEP1(T, LG) { \
            float v0 = a0 + tc0, v1 = a1 + tc1; \
            float nj = fmaxf(v0, v1) + (LG); \
            s_alpha1[T][j] = nj; \
            a0 = rl(nj, 0); a1 = rl(nj, 1); }

            for (int t = 1; t < 8 && t < sl; ++t) {
                float lg = s_l1[t][j];
                VSTEP1(t, lg);
            }
            int t0 = 8;
            for (; t0 + 8 <= sl; t0 += 8) {
                float l0 = s_l1[t0 + 0][j], l1 = s_l1[t0 + 1][j];
                float l2 = s_l1[t0 + 2][j], l3 = s_l1[t0 + 3][j];
                float l4 = s_l1[t0 + 4][j], l5 = s_l1[t0 + 5][j];
                float l6 = s_l1[t0 + 6][j], l7 = s_l1[t0 + 7][j];
                VSTEP1(t0 + 0, l0); VSTEP1(t0 + 1, l1);
                VSTEP1(t0 + 2, l2); VSTEP1(t0 + 3, l3);
                VSTEP1(t0 + 4, l4); VSTEP1(t0 + 5, l5);
                VSTEP1(t0 + 6, l6); VSTEP1(t0 + 7, l7);
            }
            for (int t = t0; t < sl; ++t) {
                float lg = s_l1[t][j];
                VSTEP1(t, lg);
            }
#undef VSTEP1
            if (lane == 0) s_last1 = (a1 > a0) ? 1 : 0;
        }
    } else {
        const int t0i = tid - 128;
        float u1 = 0.f, bs1 = 0.f, u2 = 0.f, bs2 = 0.f;
        for (int t = t0i; t < sl; t += 128) {
            int lb = s_lab[t]; int lb1 = lb > 0 ? 1 : 0;
            u1 += s_l1[t][lb1];
            u2 += s_l2[t][lb];
            if (t >= 1) {
                int lp = s_lab[t - 1]; int lp1 = lp > 0 ? 1 : 0;
                bs1 += s_tr1[lp1 * 2 + lb1];
                bs2 += s_tr2[lp * 9 + lb];
            }
        }
        for (int off = 32; off; off >>= 1) {
            u1 += __shfl_down(u1, off); bs1 += __shfl_down(bs1, off);
            u2 += __shfl_down(u2, off); bs2 += __shfl_down(bs2, off);
        }
        if (lane == 0) {
            s_part[wave - 2][0] = u1; s_part[wave - 2][1] = bs1;
            s_part[wave - 2][2] = u2; s_part[wave - 2][3] = bs2;
        }
    }
    __syncthreads();

    // phase 2: parallel bp reconstruction (bit-exact) + ll folds on wave 3
    if (tid < 189) {
        const int j = tid % 9;           // 21 threads per column
        const int tq = tid / 9;
        float tc0 = s_tr2[0 * 9 + j], tc1 = s_tr2[1 * 9 + j], tc2 = s_tr2[2 * 9 + j];
        float tc3 = s_tr2[3 * 9 + j], tc4 = s_tr2[4 * 9 + j], tc5 = s_tr2[5 * 9 + j];
        float tc6 = s_tr2[6 * 9 + j], tc7 = s_tr2[7 * 9 + j], tc8 = s_tr2[8 * 9 + j];
        for (int t = 1 + tq; t < sl; t += 21) {
            const float* ap = &s_alpha2[t - 1][0];
            float v0 = ap[0] + tc0, v1 = ap[1] + tc1, v2 = ap[2] + tc2;
            float v3 = ap[3] + tc3, v4 = ap[4] + tc4, v5 = ap[5] + tc5;
            float v6 = ap[6] + tc6, v7 = ap[7] + tc7, v8 = ap[8] + tc8;
            float mm = fmax3(fmax3(v0, v1, v2), fmax3(v3, v4, v5), fmax3(v6, v7, v8));
            int c0 = (v0 == mm) ? 0 : 15, c1 = (v1 == mm) ? 1 : 15, c2 = (v2 == mm) ? 2 : 15;
            int c3 = (v3 == mm) ? 3 : 15, c4 = (v4 == mm) ? 4 : 15, c5 = (v5 == mm) ? 5 : 15;
            int c6 = (v6 == mm) ? 6 : 15, c7 = (v7 == mm) ? 7 : 15, c8 = (v8 == mm) ? 8 : 15;
            int bi = imin3(imin3(c0, c1, c2), imin3(c3, c4, c5), imin3(c6, c7, c8));
            s_bp2[j][t] = (unsigned char)bi;
        }
    } else if (tid >= 192 && tid < 224) {
        const int kk = tid - 192;
        const int j1 = kk & 1, tq = kk >> 1;   // 16 per state
        float t10 = s_tr1[0 * 2 + j1], t11 = s_tr1[1 * 2 + j1];
        for (int t = 1 + tq; t < sl; t += 16) {
            float v0 = s_alpha1[t - 1][0] + t10;
            float v1 = s_alpha1[t - 1][1] + t11;
            s_bp1[j1][t] = (unsigned char)((v1 > v0) ? 1 : 0);
        }
    } else if (tid >= 224 && tid < 233) {
        // CRF2 log-norm fold over 16 chunk matrices (lanes 32..40 of wave 3)
        const int r = tid - 224;
        float av = s_l2[0][r];
        float a0 = rl(av, 32), a1 = rl(av, 33), a2 = rl(av, 34);
        float a3 = rl(av, 35), a4 = rl(av, 36), a5 = rl(av, 37);
        float a6 = rl(av, 38), a7 = rl(av, 39), a8 = rl(av, 40);
        for (int cc = 0; cc < 16; ++cc) {
            const float* M = &sM2[cc * 81];
            float v0 = a0 + M[0 * 9 + r], v1 = a1 + M[1 * 9 + r], v2 = a2 + M[2 * 9 + r];
            float v3 = a3 + M[3 * 9 + r], v4 = a4 + M[4 * 9 + r], v5 = a5 + M[5 * 9 + r];
            float v6 = a6 + M[6 * 9 + r], v7 = a7 + M[7 * 9 + r], v8 = a8 + M[8 * 9 + r];
            float m = fmax3(fmax3(v0, v1, v2), fmax3(v3, v4, v5), fmax3(v6, v7, v8));
            float su = __expf(v0 - m) + __expf(v1 - m) + __expf(v2 - m)
                     + __expf(v3 - m) + __expf(v4 - m) + __expf(v5 - m)
                     + __expf(v6 - m) + __expf(v7 - m) + __expf(v8 - m);
            float na = m + __logf(su);
            a0 = rl(na, 32); a1 = rl(na, 33); a2 = rl(na, 34);
            a3 = rl(na, 35); a4 = rl(na, 36); a5 = rl(na, 37);
            a6 = rl(na, 38); a7 = rl(na, 39); a8 = rl(na, 40);
        }
        if (r == 0) {
            float m = fmax3(fmax3(a0, a1, a2), fmax3(a3, a4, a5), fmax3(a6, a7, a8));
            float su = __expf(a0 - m) + __expf(a1 - m) + __expf(a2 - m)
                     + __expf(a3 - m) + __expf(a4 - m) + __expf(a5 - m)
                     + __expf(a6 - m) + __expf(a7 - m) + __expf(a8 - m);
            float ln = m + __logf(su);
            ll2[b] = (s_part[0][2] + s_part[1][2] + s_part[0][3] + s_part[1][3]) - ln;
        }
    } else if (tid >= 240 && tid < 242) {
        // CRF1 log-norm fold (lanes 48,49 of wave 3)
        const int jj = tid - 240;
        float av = s_l1[0][jj];
        float a0 = rl(av, 48), a1 = rl(av, 49);
        for (int cc = 0; cc < 16; ++cc) {
            const float* M = &sM1[cc * 4];
            float v0 = a0 + M[0 * 2 + jj], v1 = a1 + M[1 * 2 + jj];
            float mm = fmaxf(v0, v1);
            float na = mm + __logf(__expf(v0 - mm) + __expf(v1 - mm));
            a0 = rl(na, 48); a1 = rl(na, 49);
        }
        if (jj == 0) {
            float mm = fmaxf(a0, a1);
            float ln = mm + __logf(__expf(a0 - mm) + __expf(a1 - mm));
            ll1[b] = (s_part[0][0] + s_part[1][0] + s_part[0][1] + s_part[1][1]) - ln;
        }
    }
    __syncthreads();

    // phase 2b: chunk-parallel backtraces
    if (tid < 144) {
        int cch = tid / 9, e = tid - cch * 9;
        int pe = (cch < 15) ? (cch + 1) * 32 : 511;
        int tag = e;
        for (int t = pe; t > cch * 32; --t) {
            tag = s_bp2[tag][t];
            s_path2[cch][e][t - 1 - cch * 32] = (unsigned char)tag;
        }
    } else if (tid >= 160 && tid < 192) {
        int k = tid - 160, cch = k >> 1, e = k & 1;
        int pe = (cch < 15) ? (cch + 1) * 32 : 511;
        int tag = e;
        for (int t = pe; t > cch * 32; --t) {
            tag = s_bp1[tag][t];
            s_path1[cch][e][t - 1 - cch * 32] = (unsigned char)tag;
        }
    }
    __syncthreads();

    // phase 3: boundary resolve
    if (tid == 0) {
        int cur = s_last2;
        for (int c = 15; c >= 0; --c) { s_sel2[c] = (unsigned char)cur; cur = s_path2[c][cur][0]; }
    } else if (tid == 1) {
        int cur = s_last1;
        for (int c = 15; c >= 0; --c) { s_sel1[c] = (unsigned char)cur; cur = s_path1[c][cur][0]; }
    }
    __syncthreads();

    // phase 4: assemble tags + accuracy counts
    {
        int c1 = 0, c2 = 0, cc = 0;
        for (int p = tid; p < TT; p += 256) {
            int ch = p >> 5;
            int v2 = (p == 511) ? s_last2 : (int)s_path2[ch][s_sel2[ch]][p & 31];
            int v1 = (p == 511) ? s_last1 : (int)s_path1[ch][s_sel1[ch]][p & 31];
            int comb = (v1 == 0) ? 0 : v2;
            dout[(size_t)b * TT + p] = (float)comb;
            if (p < sl) {
                int lb = s_lab[p]; int lb1 = lb > 0 ? 1 : 0;
                c1 += (v1 == lb1); c2 += (v2 == lb); cc += (comb == lb);
            }
        }
        for (int off = 32; off; off >>= 1) {
            c1 += __shfl_down(c1, off); c2 += __shfl_down(c2, off); cc += __shfl_down(cc, off);
        }
        if (lane == 0) { s_cnt[wave][0] = c1; s_cnt[wave][1] = c2; s_cnt[wave][2] = cc; }
    }
    __syncthreads();
    if (tid == 0) {
        counts[b * 3 + 0] = (float)(s_cnt[0][0] + s_cnt[1][0] + s_cnt[2][0] + s_cnt[3][0]);
        counts[b * 3 + 1] = (float)(s_cnt[0][1] + s_cnt[1][1] + s_cnt[2][1] + s_cnt[3][1]);
        counts[b * 3 + 2] = (float)(s_cnt[0][2] + s_cnt[1][2] + s_cnt[2][2] + s_cnt[3][2]);
    }
}

// ---------------------------------------------------------------------------
// Kernel 3: final scalar reduction (1 block, 64 threads)
// ---------------------------------------------------------------------------
__global__ __launch_bounds__(64) void reduce_kernel(
    const float* __restrict__ ll1, const float* __restrict__ ll2,
    const float* __restrict__ counts, const int* __restrict__ seqlen,
    float* __restrict__ out)
{
    const int t = threadIdx.x;
    float v1 = ll1[t], v2 = ll2[t];
    float a1 = counts[t * 3 + 0], a2 = counts[t * 3 + 1], ac = counts[t * 3 + 2];
    float slf = (float)seqlen[t];
    for (int off = 32; off; off >>= 1) {
        v1 += __shfl_down(v1, off); v2 += __shfl_down(v2, off);
        a1 += __shfl_down(a1, off); a2 += __shfl_down(a2, off);
        ac += __shfl_down(ac, off); slf += __shfl_down(slf, off);
    }
    if (t == 0) {
        float loss1 = -v1 / 64.f;
        float loss2 = -v2 / 64.f;
        out[BB * TT + 0] = (loss1 + 8.f * loss2) / 9.f;
        out[BB * TT + 1] = a1 / slf;
        out[BB * TT + 2] = a2 / slf;
        out[BB * TT + 3] = ac / slf;
    }
}

extern "C" void kernel_launch(void* const* d_in, const int* in_sizes, int n_in,
                              void* d_out, int out_size, void* d_ws, size_t ws_size,
                              hipStream_t stream) {
    (void)in_sizes; (void)n_in; (void)out_size; (void)ws_size;
    const float* x      = (const float*)d_in[0];
    const int*   label  = (const int*)d_in[1];
    const int*   seqlen = (const int*)d_in[2];
    const float* W1     = (const float*)d_in[3];
    const float* b1     = (const float*)d_in[4];
    const float* W2     = (const float*)d_in[5];
    const float* b2     = (const float*)d_in[6];
    const float* trans1 = (const float*)d_in[7];
    const float* trans2 = (const float*)d_in[8];
    float* out = (float*)d_out;
    float* ws  = (float*)d_ws;

    float* o1     = ws;                      // 65536
    float* o2     = o1 + BB * TT * 2;        // 294912
    float* M2     = o2 + BB * TT * 9;        // 64*16*81 = 82944
    float* M1     = M2 + 64 * 16 * 81;       // 4096
    float* counts = M1 + 64 * 16 * 4;        // 192
    float* ll1    = counts + 64 * 3;         // 64
    float* ll2    = ll1 + BB;                // 64

    gemm_lse_kernel<<<512, 256, 0, stream>>>(x, W1, b1, W2, b2, seqlen,
                                             trans1, trans2, o1, o2, M1, M2);
    viterbi_kernel<<<64, 256, 0, stream>>>(o1, o2, label, seqlen, trans1, trans2,
                                           M1, M2, out, counts, ll1, ll2);
    reduce_kernel<<<1, 64, 0, stream>>>(ll1, ll2, counts, seqlen, out);
}